// Round 3
// baseline (474.534 us; speedup 1.0000x reference)
//
#include <hip/hip_runtime.h>
#include <hip/hip_bf16.h>
#include <cstddef>

#define NN 2000
#define CC 4
#define LL1 5000
#define LL2 1248   /* (5000-11)/4+1 */
#define LL3 207    /* (1248-11)/6+1 */
#define HH 512
#define EE 64000

__device__ __forceinline__ float bf2f(unsigned short v) {
    return __uint_as_float(((unsigned int)v) << 16);
}

// ---------------- device-global scratch (fixed sizes; no d_ws dependence) ----------------
__device__ float g_feat[NN * LL3];
__device__ float g_hgcn[NN * HH];
__device__ float g_z[NN * HH];
__device__ float g_xl[NN * HH];
__device__ float g_gpre[NN * HH];
__device__ float g_obuf[NN * HH];
__device__ float g_dinv[NN];
__device__ float g_colsum[HH];
__device__ float g_colsq[HH];
__device__ float g_sc[HH];
__device__ float g_sh[HH];
__device__ int   g_cnt[NN];
__device__ int   g_cursor[NN];
__device__ int   g_off[NN];
__device__ int   g_bucket[EE];

// ---------------- zero / init (must run every call; graph replay reuses globals) --------
__global__ void zero_init() {
    int i = blockIdx.x * 256 + threadIdx.x;
    if (i < NN) { g_cnt[i] = 0; g_cursor[i] = 0; }
    if (i < HH) { g_colsum[i] = 0.f; g_colsq[i] = 0.f; }
}

// ---------------- per-node conv chain ----------------
__global__ __launch_bounds__(256) void conv_chain(
    const float* __restrict__ x,
    const float* __restrict__ w1, const float* __restrict__ b1,
    const float* __restrict__ w2, const float* __restrict__ b2,
    const float* __restrict__ w3, const float* __restrict__ b3)
{
    __shared__ __align__(16) __hip_bfloat16 sm[4 * LL1];   // 40 KB pooled conv1 out (bf16)
    __shared__ float sy[4 * LL2];                           // 19.97 KB conv2 out (fp32)
    __shared__ float sw2[176], sw3[44];
    __shared__ float sb2[4], sb3v[1];

    const int tid = threadIdx.x;
    const int node = blockIdx.x;

    if (tid < 176) sw2[tid] = w2[tid];
    if (tid < 44) sw3[tid] = w3[tid];
    if (tid < 4) sb2[tid] = b2[tid];
    if (tid == 0) sb3v[0] = b3[0];
    __syncthreads();

    // conv1 weights straight from global (tiny, L2-resident)
    float w1r[64], b1r[16];
#pragma unroll
    for (int i = 0; i < 64; ++i) w1r[i] = w1[i];
#pragma unroll
    for (int i = 0; i < 16; ++i) b1r[i] = b1[i];

    // Phase 1: pointwise conv 4->16 + relu + group-of-4 channel max (relu(max)=max(relu))
    const float* xb = x + (size_t)node * (CC * LL1);
    for (int l = tid; l < LL1; l += 256) {
        float x0 = xb[l];
        float x1 = xb[LL1 + l];
        float x2 = xb[2 * LL1 + l];
        float x3 = xb[3 * LL1 + l];
#pragma unroll
        for (int g = 0; g < 4; ++g) {
            float mx = -1e30f;
#pragma unroll
            for (int j = 0; j < 4; ++j) {
                int o = g * 4 + j;
                float v = b1r[o] + w1r[o*4+0]*x0 + w1r[o*4+1]*x1 + w1r[o*4+2]*x2 + w1r[o*4+3]*x3;
                mx = fmaxf(mx, v);
            }
            sm[g * LL1 + l] = __float2bfloat16(fmaxf(mx, 0.f));
        }
    }
    __syncthreads();

    // Phase 2: conv k=11 s=4, 4->4 ch, relu. Packed 2x-bf16 uint reads from LDS.
    const unsigned int* smu = (const unsigned int*)sm;
    for (int o = 0; o < 4; ++o) {
        float wo[44];
#pragma unroll
        for (int i = 0; i < 44; ++i) wo[i] = sw2[o * 44 + i];
        float bo = sb2[o];
        for (int t = tid; t < LL2; t += 256) {
            float acc = bo;
#pragma unroll
            for (int i = 0; i < 4; ++i) {
                int ub = i * (LL1 / 2) + 2 * t;   // uint index of m[i][4t]
                float v[12];
#pragma unroll
                for (int q = 0; q < 6; ++q) {
                    unsigned int u = smu[ub + q];
                    v[2*q]   = bf2f((unsigned short)(u & 0xffffu));
                    v[2*q+1] = bf2f((unsigned short)(u >> 16));
                }
#pragma unroll
                for (int k = 0; k < 11; ++k) acc += wo[i * 11 + k] * v[k];
            }
            sy[o * LL2 + t] = fmaxf(acc, 0.f);
        }
    }
    __syncthreads();

    // Phase 3: conv k=11 s=6, 4->1, relu -> feat
    if (tid < LL3) {
        float acc = sb3v[0];
#pragma unroll
        for (int i = 0; i < 4; ++i)
#pragma unroll
            for (int k = 0; k < 11; ++k)
                acc += sw3[i * 11 + k] * sy[i * LL2 + 6 * tid + k];
        g_feat[(size_t)node * LL3 + tid] = fmaxf(acc, 0.f);
    }
}

// ---------------- edge processing ----------------
__global__ void edge_count(const int* __restrict__ ei, int E) {
    int e = blockIdx.x * 256 + threadIdx.x;
    if (e < E) atomicAdd(&g_cnt[ei[E + e]], 1);
}

__global__ __launch_bounds__(256) void scan_dinv() {
    __shared__ int a[2048], b[2048];
    int tid = threadIdx.x;
    for (int i = tid; i < 2048; i += 256) a[i] = (i < NN) ? g_cnt[i] : 0;
    __syncthreads();
    int* src = a; int* dst = b;
    for (int d = 1; d < 2048; d <<= 1) {
        for (int i = tid; i < 2048; i += 256)
            dst[i] = src[i] + ((i >= d) ? src[i - d] : 0);
        __syncthreads();
        int* t = src; src = dst; dst = t;
    }
    for (int i = tid; i < NN; i += 256) {
        g_off[i] = src[i] - g_cnt[i];                 // exclusive prefix
        g_dinv[i] = rsqrtf(1.0f + (float)g_cnt[i]);   // deg includes self loop
    }
}

__global__ void bucket_fill(const int* __restrict__ ei, int E) {
    int e = blockIdx.x * 256 + threadIdx.x;
    if (e < E) {
        int d = ei[E + e];
        int p = atomicAdd(&g_cursor[d], 1);
        g_bucket[g_off[d] + p] = ei[e];
    }
}

// ---------------- GEMM: C(MxN) = A(MxK) * B(KxN) [+bias], all fp32 ----------------
__global__ __launch_bounds__(256) void gemm_bias(
    const float* __restrict__ A, const float* __restrict__ B,
    const float* __restrict__ bias, float* __restrict__ C,
    int M, int N, int K)
{
    __shared__ float As[16][64];
    __shared__ float Bs[16][64];
    const int tid = threadIdx.x;
    const int tx = tid & 15, ty = tid >> 4;
    const int N0 = blockIdx.x * 64, M0 = blockIdx.y * 64;
    float acc[4][4] = {};

    const int am = tid >> 2, ak = (tid & 3) * 4;
    const int bk = tid >> 4, bn = (tid & 15) * 4;

    for (int k0 = 0; k0 < K; k0 += 16) {
        int r = M0 + am;
#pragma unroll
        for (int j = 0; j < 4; ++j) {
            int kk = k0 + ak + j;
            As[ak + j][am] = (r < M && kk < K) ? A[(size_t)r * K + kk] : 0.f;
        }
        {
            int kk = k0 + bk;
            float4 u = make_float4(0.f, 0.f, 0.f, 0.f);
            if (kk < K) u = *(const float4*)(B + (size_t)kk * N + N0 + bn);
            Bs[bk][bn] = u.x; Bs[bk][bn + 1] = u.y; Bs[bk][bn + 2] = u.z; Bs[bk][bn + 3] = u.w;
        }
        __syncthreads();
#pragma unroll
        for (int k = 0; k < 16; ++k) {
            float4 a4 = *(const float4*)&As[k][ty * 4];
            float4 b4 = *(const float4*)&Bs[k][tx * 4];
            acc[0][0] += a4.x * b4.x; acc[0][1] += a4.x * b4.y; acc[0][2] += a4.x * b4.z; acc[0][3] += a4.x * b4.w;
            acc[1][0] += a4.y * b4.x; acc[1][1] += a4.y * b4.y; acc[1][2] += a4.y * b4.z; acc[1][3] += a4.y * b4.w;
            acc[2][0] += a4.z * b4.x; acc[2][1] += a4.z * b4.y; acc[2][2] += a4.z * b4.z; acc[2][3] += a4.z * b4.w;
            acc[3][0] += a4.w * b4.x; acc[3][1] += a4.w * b4.y; acc[3][2] += a4.w * b4.z; acc[3][3] += a4.w * b4.w;
        }
        __syncthreads();
    }

    float bb[4];
#pragma unroll
    for (int j = 0; j < 4; ++j)
        bb[j] = bias ? bias[N0 + tx * 4 + j] : 0.f;
#pragma unroll
    for (int i = 0; i < 4; ++i) {
        int r = M0 + ty * 4 + i;
        if (r < M) {
#pragma unroll
            for (int j = 0; j < 4; ++j)
                C[(size_t)r * N + N0 + tx * 4 + j] = acc[i][j] + bb[j];
        }
    }
}

// ---------------- GCN aggregate + bias + tanh ----------------
__global__ __launch_bounds__(256) void gcn_agg(const float* __restrict__ gcn_b)
{
    const int d = blockIdx.x;
    const int tid = threadIdx.x;
    const float di = g_dinv[d];
    const int nb = g_cnt[d];
    const int base = g_off[d];
    const float* __restrict__ h = g_hgcn;
    float acc0 = h[(size_t)d * HH + tid] * di;          // self loop
    float acc1 = h[(size_t)d * HH + tid + 256] * di;
    for (int j = 0; j < nb; ++j) {
        int s = g_bucket[base + j];
        float ws = g_dinv[s];
        acc0 += h[(size_t)s * HH + tid] * ws;
        acc1 += h[(size_t)s * HH + tid + 256] * ws;
    }
    acc0 = tanhf(acc0 * di + gcn_b[tid]);
    acc1 = tanhf(acc1 * di + gcn_b[tid + 256]);
    g_z[(size_t)d * HH + tid] = acc0;
    g_z[(size_t)d * HH + tid + 256] = acc1;
}

// ---------------- gate + residual + relu + column sums ----------------
__global__ __launch_bounds__(256) void gate_bn()
{
    const int tid = threadIdx.x;
    const int r0 = blockIdx.x * 8;
    float a0 = 0, a1 = 0, q0 = 0, q1 = 0;
    for (int r = r0; r < r0 + 8; ++r) {
        size_t i0 = (size_t)r * HH + tid;
        size_t i1 = i0 + 256;
        float g0 = 1.f / (1.f + expf(-g_gpre[i0]));
        float g1 = 1.f / (1.f + expf(-g_gpre[i1]));
        float v0 = fmaxf((1.f - g0) * g_xl[i0] + g0 * g_z[i0], 0.f);
        float v1 = fmaxf((1.f - g1) * g_xl[i1] + g1 * g_z[i1], 0.f);
        g_obuf[i0] = v0; g_obuf[i1] = v1;
        a0 += v0; q0 += v0 * v0;
        a1 += v1; q1 += v1 * v1;
    }
    atomicAdd(&g_colsum[tid], a0);
    atomicAdd(&g_colsum[tid + 256], a1);
    atomicAdd(&g_colsq[tid], q0);
    atomicAdd(&g_colsq[tid + 256], q1);
}

__global__ void bn_stats(const float* __restrict__ gamma,
                         const float* __restrict__ beta) {
    int c = threadIdx.x;  // 512
    float mean = g_colsum[c] * (1.f / (float)NN);
    float var = g_colsq[c] * (1.f / (float)NN) - mean * mean;
    float s = rsqrtf(var + 1e-5f) * gamma[c];
    g_sc[c] = s;
    g_sh[c] = beta[c] - mean * s;
}

__global__ __launch_bounds__(256) void bn_apply(float* __restrict__ out) {
    int i = blockIdx.x * 256 + threadIdx.x;  // exactly NN*HH
    int c = i & (HH - 1);
    out[i] = g_obuf[i] * g_sc[c] + g_sh[c];
}

// ---------------- launch ----------------
extern "C" void kernel_launch(void* const* d_in, const int* in_sizes, int n_in,
                              void* d_out, int out_size, void* d_ws, size_t ws_size,
                              hipStream_t stream) {
    const float* x      = (const float*)d_in[0];
    const int*   ei     = (const int*)d_in[1];
    const float* w1     = (const float*)d_in[2];
    const float* b1     = (const float*)d_in[3];
    const float* w2     = (const float*)d_in[4];
    const float* b2     = (const float*)d_in[5];
    const float* w3     = (const float*)d_in[6];
    const float* b3     = (const float*)d_in[7];
    const float* gcn_w  = (const float*)d_in[8];
    const float* gcn_b  = (const float*)d_in[9];
    const float* lin_w  = (const float*)d_in[10];
    const float* lin_b  = (const float*)d_in[11];
    const float* gate_w = (const float*)d_in[12];
    const float* gate_b = (const float*)d_in[13];
    const float* bn_g   = (const float*)d_in[14];
    const float* bn_b   = (const float*)d_in[15];
    float* out = (float*)d_out;
    const int E = in_sizes[1] / 2;

    // resolve device-global scratch addresses for kernels that take pointers
    float* feat = nullptr; float* hgcn = nullptr; float* z = nullptr;
    float* xl = nullptr; float* gpre = nullptr;
    hipGetSymbolAddress((void**)&feat, HIP_SYMBOL(g_feat));
    hipGetSymbolAddress((void**)&hgcn, HIP_SYMBOL(g_hgcn));
    hipGetSymbolAddress((void**)&z,    HIP_SYMBOL(g_z));
    hipGetSymbolAddress((void**)&xl,   HIP_SYMBOL(g_xl));
    hipGetSymbolAddress((void**)&gpre, HIP_SYMBOL(g_gpre));

    zero_init<<<8, 256, 0, stream>>>();
    conv_chain<<<NN, 256, 0, stream>>>(x, w1, b1, w2, b2, w3, b3);
    edge_count<<<(E + 255) / 256, 256, 0, stream>>>(ei, E);
    scan_dinv<<<1, 256, 0, stream>>>();
    bucket_fill<<<(E + 255) / 256, 256, 0, stream>>>(ei, E);

    dim3 g1(HH / 64, (NN + 63) / 64);
    gemm_bias<<<g1, 256, 0, stream>>>(feat, gcn_w, nullptr, hgcn, NN, HH, LL3);
    gcn_agg<<<NN, 256, 0, stream>>>(gcn_b);
    gemm_bias<<<g1, 256, 0, stream>>>(feat, lin_w, lin_b, xl, NN, HH, LL3);
    gemm_bias<<<g1, 256, 0, stream>>>(z, gate_w, gate_b, gpre, NN, HH, HH);

    gate_bn<<<NN / 8, 256, 0, stream>>>();
    bn_stats<<<1, HH, 0, stream>>>(bn_g, bn_b);
    bn_apply<<<(NN * HH) / 256, 256, 0, stream>>>(out);
}

// Round 4
// 406.424 us; speedup vs baseline: 1.1676x; 1.1676x over previous
//
#include <hip/hip_runtime.h>
#include <hip/hip_bf16.h>
#include <cstddef>

#define NN 2000
#define CC 4
#define LL1 5000
#define LL2 1248   /* (5000-11)/4+1 */
#define LL3 207    /* (1248-11)/6+1 */
#define HH 512
#define EE 64000

__device__ __forceinline__ float bf2f_lo(unsigned int u) { return __uint_as_float(u << 16); }
__device__ __forceinline__ float bf2f_hi(unsigned int u) { return __uint_as_float(u & 0xffff0000u); }
__device__ __forceinline__ unsigned int f2bf(float v) {
    __hip_bfloat16 h = __float2bfloat16(v);
    unsigned short u; __builtin_memcpy(&u, &h, 2);
    return (unsigned int)u;
}

// ---------------- device-global scratch ----------------
__device__ float g_feat[NN * LL3];
__device__ float g_aggf[NN * LL3];
__device__ float g_z[NN * HH];
__device__ float g_xl[NN * HH];
__device__ float g_gpre[NN * HH];
__device__ float g_obuf[NN * HH];
__device__ float g_dinv[NN];
__device__ float g_colsum[HH];
__device__ float g_colsq[HH];
__device__ float g_sc[HH];
__device__ float g_sh[HH];
__device__ int   g_cnt[NN];
__device__ int   g_cursor[NN];
__device__ int   g_off[NN];
__device__ int   g_bucket[EE];

// ---------------- zero / init (every call; graph replay reuses globals) --------
__global__ void zero_init() {
    int i = blockIdx.x * 256 + threadIdx.x;
    if (i < NN) { g_cnt[i] = 0; g_cursor[i] = 0; }
    if (i < HH) { g_colsum[i] = 0.f; g_colsq[i] = 0.f; }
}

// ---------------- per-node conv chain (split-L, 40.1KB LDS -> 4 blocks/CU) ----------------
// half-buffer: per channel 2512 bf16 values = 1256 dwords; 4 ch = 20096 B
#define HB_DW 1256
#define HB_U2 628
__global__ __launch_bounds__(256) void conv_chain(
    const float* __restrict__ x,
    const float* __restrict__ w1, const float* __restrict__ b1,
    const float* __restrict__ w2, const float* __restrict__ b2,
    const float* __restrict__ w3, const float* __restrict__ b3)
{
    __shared__ __align__(16) unsigned int smu[4 * HB_DW];  // 20096 B (bf16-packed m, half L)
    __shared__ float sy[4 * LL2];                          // 19968 B (conv2 out fp32)

    const int tid = threadIdx.x;
    const int node = blockIdx.x;
    const float* xb = x + (size_t)node * (CC * LL1);

    // conv1 weights (wave-uniform -> scalar regs)
    float w1r[64], b1r[16];
#pragma unroll
    for (int i = 0; i < 64; ++i) w1r[i] = w1[i];
#pragma unroll
    for (int i = 0; i < 16; ++i) b1r[i] = b1[i];

    uint2* smu2 = (uint2*)smu;

    for (int h = 0; h < 2; ++h) {
        const int l0 = h * 2496;
        // ---- Phase 1: pointwise conv 4->16 + relu + group-max, 4 l's per iter ----
        for (int g4 = tid; g4 < 626; g4 += 256) {
            const int l = l0 + 4 * g4;
            float xs[4][4];
#pragma unroll
            for (int c = 0; c < 4; ++c)
                *(float4*)xs[c] = *(const float4*)(xb + c * LL1 + l);
#pragma unroll
            for (int g = 0; g < 4; ++g) {
                float mv[4];
#pragma unroll
                for (int li = 0; li < 4; ++li) {
                    float best = -1e30f;
#pragma unroll
                    for (int j = 0; j < 4; ++j) {
                        int o = g * 4 + j;
                        float v = b1r[o] + w1r[o*4+0]*xs[0][li] + w1r[o*4+1]*xs[1][li]
                                         + w1r[o*4+2]*xs[2][li] + w1r[o*4+3]*xs[3][li];
                        best = fmaxf(best, v);
                    }
                    mv[li] = fmaxf(best, 0.f);
                }
                uint2 p;
                p.x = f2bf(mv[0]) | (f2bf(mv[1]) << 16);
                p.y = f2bf(mv[2]) | (f2bf(mv[3]) << 16);
                smu2[g * HB_U2 + g4] = p;
            }
        }
        __syncthreads();

        // ---- Phase 2: conv k=11 s=4, 4ch->4ch, relu. One window unpack serves all 4 o. ----
        const int T0 = h * 624;
        for (int t = T0 + tid; t < T0 + 624; t += 256) {
            const int T = t - T0;                  // local window start /4
            float acc0 = b2[0], acc1 = b2[1], acc2 = b2[2], acc3 = b2[3];
#pragma unroll
            for (int i = 0; i < 4; ++i) {
                const int ub = i * HB_U2 + T;
                uint2 r0 = smu2[ub], r1 = smu2[ub + 1], r2 = smu2[ub + 2];
                float v[12];
                v[0] = bf2f_lo(r0.x); v[1] = bf2f_hi(r0.x);
                v[2] = bf2f_lo(r0.y); v[3] = bf2f_hi(r0.y);
                v[4] = bf2f_lo(r1.x); v[5] = bf2f_hi(r1.x);
                v[6] = bf2f_lo(r1.y); v[7] = bf2f_hi(r1.y);
                v[8] = bf2f_lo(r2.x); v[9] = bf2f_hi(r2.x);
                v[10] = bf2f_lo(r2.y); v[11] = bf2f_hi(r2.y);
#pragma unroll
                for (int k = 0; k < 11; ++k) {
                    float vv = v[k];
                    acc0 += w2[0*44 + i*11 + k] * vv;
                    acc1 += w2[1*44 + i*11 + k] * vv;
                    acc2 += w2[2*44 + i*11 + k] * vv;
                    acc3 += w2[3*44 + i*11 + k] * vv;
                }
            }
            sy[0 * LL2 + t] = fmaxf(acc0, 0.f);
            sy[1 * LL2 + t] = fmaxf(acc1, 0.f);
            sy[2 * LL2 + t] = fmaxf(acc2, 0.f);
            sy[3 * LL2 + t] = fmaxf(acc3, 0.f);
        }
        __syncthreads();   // also protects smu overwrite in next half
    }

    // ---- Phase 3: conv k=11 s=6, 4->1, relu -> feat ----
    if (tid < LL3) {
        float acc = b3[0];
#pragma unroll
        for (int i = 0; i < 4; ++i)
#pragma unroll
            for (int k = 0; k < 11; ++k)
                acc += w3[i * 11 + k] * sy[i * LL2 + 6 * tid + k];
        g_feat[(size_t)node * LL3 + tid] = fmaxf(acc, 0.f);
    }
}

// ---------------- edge processing ----------------
__global__ void edge_count(const int* __restrict__ ei, int E) {
    int e = blockIdx.x * 256 + threadIdx.x;
    if (e < E) atomicAdd(&g_cnt[ei[E + e]], 1);
}

__global__ __launch_bounds__(256) void scan_dinv() {
    __shared__ int a[2048], b[2048];
    int tid = threadIdx.x;
    for (int i = tid; i < 2048; i += 256) a[i] = (i < NN) ? g_cnt[i] : 0;
    __syncthreads();
    int* src = a; int* dst = b;
    for (int d = 1; d < 2048; d <<= 1) {
        for (int i = tid; i < 2048; i += 256)
            dst[i] = src[i] + ((i >= d) ? src[i - d] : 0);
        __syncthreads();
        int* t = src; src = dst; dst = t;
    }
    for (int i = tid; i < NN; i += 256) {
        g_off[i] = src[i] - g_cnt[i];
        g_dinv[i] = rsqrtf(1.0f + (float)g_cnt[i]);
    }
}

__global__ void bucket_fill(const int* __restrict__ ei, int E) {
    int e = blockIdx.x * 256 + threadIdx.x;
    if (e < E) {
        int d = ei[E + e];
        int p = atomicAdd(&g_cursor[d], 1);
        g_bucket[g_off[d] + p] = ei[e];
    }
}

// ---------------- aggregate feat over graph (agg-before-GEMM: 207 cols not 512) -------
__global__ __launch_bounds__(256) void agg_feat() {
    const int d = blockIdx.x;
    const int tid = threadIdx.x;
    if (tid >= LL3) return;
    const float di = g_dinv[d];
    const int nb = g_cnt[d];
    const int base = g_off[d];
    float acc = g_feat[(size_t)d * LL3 + tid] * di;
    int j = 0;
    for (; j + 1 < nb; j += 2) {
        int s0 = g_bucket[base + j];
        int s1 = g_bucket[base + j + 1];
        acc += g_feat[(size_t)s0 * LL3 + tid] * g_dinv[s0]
             + g_feat[(size_t)s1 * LL3 + tid] * g_dinv[s1];
    }
    if (j < nb) {
        int s = g_bucket[base + j];
        acc += g_feat[(size_t)s * LL3 + tid] * g_dinv[s];
    }
    g_aggf[(size_t)d * LL3 + tid] = acc * di;
}

// ---------------- GEMM: C(MxN) = A(MxK)*B(KxN) + bias [,tanh], 32x64 tile, dbuf ------
template<int EPI>   // 0 = bias only, 1 = bias + tanh
__global__ __launch_bounds__(256) void gemm32(
    const float* __restrict__ A, const float* __restrict__ B,
    const float* __restrict__ bias, float* __restrict__ C,
    int M, int N, int K)
{
    __shared__ float As[2][16][32];
    __shared__ float Bs[2][16][64];
    const int tid = threadIdx.x;
    const int N0 = blockIdx.x * 64, M0 = blockIdx.y * 32;
    const int tx = tid & 15, ty = tid >> 4;
    const int ar = tid >> 3, ak = (tid & 7) * 2;
    const int bk = tid >> 4, bn = (tid & 15) * 4;
    const int NT = (K + 15) / 16;

    float acc[2][4] = {};
    float a0, a1; float4 b4r;

    // load tile 0
    {
        int r = M0 + ar;
        a0 = (r < M && ak < K) ? A[(size_t)r * K + ak] : 0.f;
        a1 = (r < M && ak + 1 < K) ? A[(size_t)r * K + ak + 1] : 0.f;
        b4r = (bk < K) ? *(const float4*)(B + (size_t)bk * N + N0 + bn) : make_float4(0,0,0,0);
        As[0][ak][ar] = a0; As[0][ak + 1][ar] = a1;
        *(float4*)&Bs[0][bk][bn] = b4r;
    }
    __syncthreads();

    for (int kt = 0; kt < NT; ++kt) {
        const int cur = kt & 1;
        if (kt + 1 < NT) {
            int k0 = (kt + 1) * 16;
            int r = M0 + ar;
            int kk = k0 + ak;
            a0 = (r < M && kk < K) ? A[(size_t)r * K + kk] : 0.f;
            a1 = (r < M && kk + 1 < K) ? A[(size_t)r * K + kk + 1] : 0.f;
            int kb = k0 + bk;
            b4r = (kb < K) ? *(const float4*)(B + (size_t)kb * N + N0 + bn) : make_float4(0,0,0,0);
        }
#pragma unroll
        for (int k = 0; k < 16; ++k) {
            float2 a2 = *(const float2*)&As[cur][k][ty * 2];
            float4 b4 = *(const float4*)&Bs[cur][k][tx * 4];
            acc[0][0] += a2.x * b4.x; acc[0][1] += a2.x * b4.y;
            acc[0][2] += a2.x * b4.z; acc[0][3] += a2.x * b4.w;
            acc[1][0] += a2.y * b4.x; acc[1][1] += a2.y * b4.y;
            acc[1][2] += a2.y * b4.z; acc[1][3] += a2.y * b4.w;
        }
        if (kt + 1 < NT) {
            const int nxt = cur ^ 1;
            As[nxt][ak][ar] = a0; As[nxt][ak + 1][ar] = a1;
            *(float4*)&Bs[nxt][bk][bn] = b4r;
        }
        __syncthreads();
    }

    float bb[4];
#pragma unroll
    for (int j = 0; j < 4; ++j) bb[j] = bias ? bias[N0 + tx * 4 + j] : 0.f;
#pragma unroll
    for (int i = 0; i < 2; ++i) {
        int r = M0 + ty * 2 + i;
        if (r < M) {
#pragma unroll
            for (int j = 0; j < 4; ++j) {
                float v = acc[i][j] + bb[j];
                if (EPI == 1) v = tanhf(v);
                C[(size_t)r * N + N0 + tx * 4 + j] = v;
            }
        }
    }
}

// ---------------- gate + residual + relu + column sums ----------------
__global__ __launch_bounds__(256) void gate_bn() {
    const int tid = threadIdx.x;
    const int r0 = blockIdx.x * 8;
    float a0 = 0, a1 = 0, q0 = 0, q1 = 0;
    for (int r = r0; r < r0 + 8; ++r) {
        size_t i0 = (size_t)r * HH + tid;
        size_t i1 = i0 + 256;
        float g0 = 1.f / (1.f + expf(-g_gpre[i0]));
        float g1 = 1.f / (1.f + expf(-g_gpre[i1]));
        float v0 = fmaxf((1.f - g0) * g_xl[i0] + g0 * g_z[i0], 0.f);
        float v1 = fmaxf((1.f - g1) * g_xl[i1] + g1 * g_z[i1], 0.f);
        g_obuf[i0] = v0; g_obuf[i1] = v1;
        a0 += v0; q0 += v0 * v0;
        a1 += v1; q1 += v1 * v1;
    }
    atomicAdd(&g_colsum[tid], a0);
    atomicAdd(&g_colsum[tid + 256], a1);
    atomicAdd(&g_colsq[tid], q0);
    atomicAdd(&g_colsq[tid + 256], q1);
}

__global__ void bn_stats(const float* __restrict__ gamma, const float* __restrict__ beta) {
    int c = threadIdx.x;  // 512
    float mean = g_colsum[c] * (1.f / (float)NN);
    float var = g_colsq[c] * (1.f / (float)NN) - mean * mean;
    float s = rsqrtf(var + 1e-5f) * gamma[c];
    g_sc[c] = s;
    g_sh[c] = beta[c] - mean * s;
}

__global__ __launch_bounds__(256) void bn_apply(float* __restrict__ out) {
    int i = blockIdx.x * 256 + threadIdx.x;  // exactly NN*HH
    int c = i & (HH - 1);
    out[i] = g_obuf[i] * g_sc[c] + g_sh[c];
}

// ---------------- launch ----------------
extern "C" void kernel_launch(void* const* d_in, const int* in_sizes, int n_in,
                              void* d_out, int out_size, void* d_ws, size_t ws_size,
                              hipStream_t stream) {
    (void)d_ws; (void)ws_size; (void)n_in; (void)out_size;
    const float* x      = (const float*)d_in[0];
    const int*   ei     = (const int*)d_in[1];
    const float* w1     = (const float*)d_in[2];
    const float* b1     = (const float*)d_in[3];
    const float* w2     = (const float*)d_in[4];
    const float* b2     = (const float*)d_in[5];
    const float* w3     = (const float*)d_in[6];
    const float* b3     = (const float*)d_in[7];
    const float* gcn_w  = (const float*)d_in[8];
    const float* gcn_b  = (const float*)d_in[9];
    const float* lin_w  = (const float*)d_in[10];
    const float* lin_b  = (const float*)d_in[11];
    const float* gate_w = (const float*)d_in[12];
    const float* gate_b = (const float*)d_in[13];
    const float* bn_g   = (const float*)d_in[14];
    const float* bn_b   = (const float*)d_in[15];
    float* out = (float*)d_out;
    const int E = in_sizes[1] / 2;

    float* feat = nullptr; float* aggf = nullptr; float* z = nullptr;
    float* xl = nullptr; float* gpre = nullptr;
    hipGetSymbolAddress((void**)&feat, HIP_SYMBOL(g_feat));
    hipGetSymbolAddress((void**)&aggf, HIP_SYMBOL(g_aggf));
    hipGetSymbolAddress((void**)&z,    HIP_SYMBOL(g_z));
    hipGetSymbolAddress((void**)&xl,   HIP_SYMBOL(g_xl));
    hipGetSymbolAddress((void**)&gpre, HIP_SYMBOL(g_gpre));

    zero_init<<<8, 256, 0, stream>>>();
    conv_chain<<<NN, 256, 0, stream>>>(x, w1, b1, w2, b2, w3, b3);
    edge_count<<<(E + 255) / 256, 256, 0, stream>>>(ei, E);
    scan_dinv<<<1, 256, 0, stream>>>();
    bucket_fill<<<(E + 255) / 256, 256, 0, stream>>>(ei, E);
    agg_feat<<<NN, 256, 0, stream>>>();

    dim3 gg(HH / 64, (NN + 31) / 32);
    gemm32<1><<<gg, 256, 0, stream>>>(aggf, gcn_w, gcn_b, z, NN, HH, LL3);     // z = tanh(Âf @ W + b)
    gemm32<0><<<gg, 256, 0, stream>>>(feat, lin_w, lin_b, xl, NN, HH, LL3);    // xl
    gemm32<0><<<gg, 256, 0, stream>>>(z, gate_w, gate_b, gpre, NN, HH, HH);    // gate pre-act

    gate_bn<<<NN / 8, 256, 0, stream>>>();
    bn_stats<<<1, HH, 0, stream>>>(bn_g, bn_b);
    bn_apply<<<(NN * HH) / 256, 256, 0, stream>>>(out);
}

// Round 5
// 386.080 us; speedup vs baseline: 1.2291x; 1.0527x over previous
//
#include <hip/hip_runtime.h>
#include <hip/hip_bf16.h>
#include <cstddef>

#define NN 2000
#define CC 4
#define LL1 5000
#define LL2 1248   /* (5000-11)/4+1 */
#define LL3 207    /* (1248-11)/6+1 */
#define HH 512
#define EE 64000

// ---------------- device-global scratch ----------------
__device__ float g_feat[NN * LL3];
__device__ float g_aggf[NN * LL3];
__device__ float g_z[NN * HH];
__device__ float g_xl[NN * HH];
__device__ float g_obuf[NN * HH];
__device__ float g_dinv[NN];
__device__ float g_colsum[HH];
__device__ float g_colsq[HH];
__device__ float g_sc[HH];
__device__ float g_sh[HH];
__device__ int   g_cnt[NN];
__device__ int   g_cursor[NN];
__device__ int   g_off[NN];
__device__ int   g_bucket[EE];

// ---------------- zero / init (every call; graph replay reuses globals) --------
__global__ void zero_init() {
    int i = blockIdx.x * 256 + threadIdx.x;
    if (i < NN) { g_cnt[i] = 0; g_cursor[i] = 0; }
    if (i < HH) { g_colsum[i] = 0.f; g_colsq[i] = 0.f; }
}

// ---------------- per-node conv chain ----------------
// m kept fp32 in LDS, L processed in 4 chunks of 1248 positions (+8 halo).
// chunk m buffer: 4ch x 1256 fp32 = 20096 B ; sy: 4 x 1248 fp32 = 19968 B -> 40.1 KB
#define MCH 1256
__global__ __launch_bounds__(256) void conv_chain(
    const float* __restrict__ x,
    const float* __restrict__ w1, const float* __restrict__ b1,
    const float* __restrict__ w2, const float* __restrict__ b2,
    const float* __restrict__ w3, const float* __restrict__ b3)
{
    __shared__ __align__(16) float sm[4 * MCH];
    __shared__ __align__(16) float sy[4 * LL2];

    const int tid = threadIdx.x;
    const int node = blockIdx.x;
    const float* xb = x + (size_t)node * (CC * LL1);

    float w1r[64], b1r[16];
#pragma unroll
    for (int i = 0; i < 64; ++i) w1r[i] = w1[i];
#pragma unroll
    for (int i = 0; i < 16; ++i) b1r[i] = b1[i];

#pragma unroll 1
    for (int c = 0; c < 4; ++c) {
        const int l0 = 1248 * c;
        // ---- Phase 1: pointwise conv 4->16 + relu + group-of-4 max, fp32 -> LDS ----
        for (int g4 = tid; g4 < 314; g4 += 256) {
            const int l = l0 + 4 * g4;           // max 3744+1252=4996, float4 in-bounds
            float xs[4][4];
#pragma unroll
            for (int ch = 0; ch < 4; ++ch)
                *(float4*)xs[ch] = *(const float4*)(xb + ch * LL1 + l);
#pragma unroll
            for (int g = 0; g < 4; ++g) {
                float mv[4];
#pragma unroll
                for (int li = 0; li < 4; ++li) {
                    float best = -1e30f;
#pragma unroll
                    for (int j = 0; j < 4; ++j) {
                        int o = g * 4 + j;
                        float v = b1r[o] + w1r[o*4+0]*xs[0][li] + w1r[o*4+1]*xs[1][li]
                                         + w1r[o*4+2]*xs[2][li] + w1r[o*4+3]*xs[3][li];
                        best = fmaxf(best, v);
                    }
                    mv[li] = fmaxf(best, 0.f);
                }
                *(float4*)&sm[g * MCH + 4 * g4] = make_float4(mv[0], mv[1], mv[2], mv[3]);
            }
        }
        __syncthreads();

        // ---- Phase 2: conv k=11 s=4, 4ch->4ch, relu. Two o-pair passes, fp32 windows. ----
        const int T0 = 312 * c;
#pragma unroll 1
        for (int pair = 0; pair < 2; ++pair) {
            const float* wp = w2 + 88 * pair;
            float wo[88];
#pragma unroll
            for (int i = 0; i < 88; ++i) wo[i] = wp[i];
            const float bo0 = b2[2 * pair], bo1 = b2[2 * pair + 1];
            for (int T = tid; T < 312; T += 256) {
                float a0 = bo0, a1 = bo1;
#pragma unroll
                for (int i = 0; i < 4; ++i) {
                    const float* mp = sm + i * MCH + 4 * T;
                    float4 u0 = *(const float4*)mp;
                    float4 u1 = *(const float4*)(mp + 4);
                    float4 u2 = *(const float4*)(mp + 8);
                    float v[12] = {u0.x, u0.y, u0.z, u0.w,
                                   u1.x, u1.y, u1.z, u1.w,
                                   u2.x, u2.y, u2.z, u2.w};
#pragma unroll
                    for (int k = 0; k < 11; ++k) {
                        a0 += wo[i * 11 + k] * v[k];
                        a1 += wo[44 + i * 11 + k] * v[k];
                    }
                }
                sy[(2 * pair) * LL2 + T0 + T]     = fmaxf(a0, 0.f);
                sy[(2 * pair + 1) * LL2 + T0 + T] = fmaxf(a1, 0.f);
            }
        }
        __syncthreads();   // protects sm overwrite next chunk; last one protects sy for P3
    }

    // ---- Phase 3: conv k=11 s=6, 4->1, relu -> feat ----
    if (tid < LL3) {
        float acc = b3[0];
#pragma unroll
        for (int i = 0; i < 4; ++i)
#pragma unroll
            for (int k = 0; k < 11; ++k)
                acc += w3[i * 11 + k] * sy[i * LL2 + 6 * tid + k];
        g_feat[(size_t)node * LL3 + tid] = fmaxf(acc, 0.f);
    }
}

// ---------------- edge processing ----------------
__global__ void edge_count(const int* __restrict__ ei, int E) {
    int e = blockIdx.x * 256 + threadIdx.x;
    if (e < E) atomicAdd(&g_cnt[ei[E + e]], 1);
}

__global__ __launch_bounds__(256) void scan_dinv() {
    __shared__ int a[2048], b[2048];
    int tid = threadIdx.x;
    for (int i = tid; i < 2048; i += 256) a[i] = (i < NN) ? g_cnt[i] : 0;
    __syncthreads();
    int* src = a; int* dst = b;
    for (int d = 1; d < 2048; d <<= 1) {
        for (int i = tid; i < 2048; i += 256)
            dst[i] = src[i] + ((i >= d) ? src[i - d] : 0);
        __syncthreads();
        int* t = src; src = dst; dst = t;
    }
    for (int i = tid; i < NN; i += 256) {
        g_off[i] = src[i] - g_cnt[i];
        g_dinv[i] = rsqrtf(1.0f + (float)g_cnt[i]);
    }
}

__global__ void bucket_fill(const int* __restrict__ ei, int E) {
    int e = blockIdx.x * 256 + threadIdx.x;
    if (e < E) {
        int d = ei[E + e];
        int p = atomicAdd(&g_cursor[d], 1);
        g_bucket[g_off[d] + p] = ei[e];
    }
}

// ---------------- aggregate feat over graph (agg-before-GEMM: 207 cols not 512) -------
__global__ __launch_bounds__(256) void agg_feat() {
    const int d = blockIdx.x;
    const int tid = threadIdx.x;
    if (tid >= LL3) return;
    const float di = g_dinv[d];
    const int nb = g_cnt[d];
    const int base = g_off[d];
    float acc = g_feat[(size_t)d * LL3 + tid] * di;
    int j = 0;
    for (; j + 1 < nb; j += 2) {
        int s0 = g_bucket[base + j];
        int s1 = g_bucket[base + j + 1];
        acc += g_feat[(size_t)s0 * LL3 + tid] * g_dinv[s0]
             + g_feat[(size_t)s1 * LL3 + tid] * g_dinv[s1];
    }
    if (j < nb) {
        int s = g_bucket[base + j];
        acc += g_feat[(size_t)s * LL3 + tid] * g_dinv[s];
    }
    g_aggf[(size_t)d * LL3 + tid] = acc * di;
}

// ---------------- GEMM: 64x64 tile, 4x4/thread, double-buffered ----------------
// EPI: 0 = bias, 1 = bias+tanh, 2 = gate epilogue (C=obuf, fused gate/relu/colsums)
template<int EPI>
__global__ __launch_bounds__(256) void gemm64(
    const float* __restrict__ A, const float* __restrict__ B,
    const float* __restrict__ bias, float* __restrict__ C,
    const float* __restrict__ xl, const float* __restrict__ zb,
    int M, int N, int K)
{
    __shared__ float As[2][16][64];
    __shared__ float Bs[2][16][64];
    __shared__ float rs[64], rq[64];
    const int tid = threadIdx.x;
    const int N0 = blockIdx.x * 64, M0 = blockIdx.y * 64;
    const int tx = tid & 15, ty = tid >> 4;
    const int ar = tid & 63, ac = (tid >> 6) * 4;   // A: 64 rows x 4 k each
    const int bk = tid >> 4, bn = (tid & 15) * 4;   // B: 16 k x 16 float4
    const int NT = (K + 15) / 16;

    float acc[4][4] = {};
    float ra[4]; float4 rb;

    {   // load tile 0
        int r = M0 + ar;
#pragma unroll
        for (int q = 0; q < 4; ++q) {
            int kk = ac + q;
            ra[q] = (r < M && kk < K) ? A[(size_t)r * K + kk] : 0.f;
        }
        rb = (bk < K) ? *(const float4*)(B + (size_t)bk * N + N0 + bn) : make_float4(0,0,0,0);
#pragma unroll
        for (int q = 0; q < 4; ++q) As[0][ac + q][ar] = ra[q];
        *(float4*)&Bs[0][bk][bn] = rb;
    }
    __syncthreads();

#pragma unroll 1
    for (int kt = 0; kt < NT; ++kt) {
        const int cur = kt & 1;
        if (kt + 1 < NT) {
            int k0 = (kt + 1) * 16;
            int r = M0 + ar;
#pragma unroll
            for (int q = 0; q < 4; ++q) {
                int kk = k0 + ac + q;
                ra[q] = (r < M && kk < K) ? A[(size_t)r * K + kk] : 0.f;
            }
            int kb = k0 + bk;
            rb = (kb < K) ? *(const float4*)(B + (size_t)kb * N + N0 + bn) : make_float4(0,0,0,0);
        }
#pragma unroll
        for (int k = 0; k < 16; ++k) {
            float4 a4 = *(const float4*)&As[cur][k][ty * 4];
            float4 b4 = *(const float4*)&Bs[cur][k][tx * 4];
            acc[0][0] += a4.x * b4.x; acc[0][1] += a4.x * b4.y; acc[0][2] += a4.x * b4.z; acc[0][3] += a4.x * b4.w;
            acc[1][0] += a4.y * b4.x; acc[1][1] += a4.y * b4.y; acc[1][2] += a4.y * b4.z; acc[1][3] += a4.y * b4.w;
            acc[2][0] += a4.z * b4.x; acc[2][1] += a4.z * b4.y; acc[2][2] += a4.z * b4.z; acc[2][3] += a4.z * b4.w;
            acc[3][0] += a4.w * b4.x; acc[3][1] += a4.w * b4.y; acc[3][2] += a4.w * b4.z; acc[3][3] += a4.w * b4.w;
        }
        if (kt + 1 < NT) {
            const int nxt = cur ^ 1;
#pragma unroll
            for (int q = 0; q < 4; ++q) As[nxt][ac + q][ar] = ra[q];
            *(float4*)&Bs[nxt][bk][bn] = rb;
        }
        __syncthreads();
    }

    const int c0 = N0 + tx * 4;
    float4 bb4 = bias ? *(const float4*)(bias + c0) : make_float4(0,0,0,0);
    float bb[4] = {bb4.x, bb4.y, bb4.z, bb4.w};

    if (EPI == 2) {
        float cs[4] = {0,0,0,0}, cq[4] = {0,0,0,0};
#pragma unroll
        for (int i = 0; i < 4; ++i) {
            int r = M0 + ty * 4 + i;
            if (r < M) {
                float4 xv = *(const float4*)(xl + (size_t)r * N + c0);
                float4 zv = *(const float4*)(zb + (size_t)r * N + c0);
                float xa[4] = {xv.x, xv.y, xv.z, xv.w};
                float za[4] = {zv.x, zv.y, zv.z, zv.w};
                float va[4];
#pragma unroll
                for (int j = 0; j < 4; ++j) {
                    float g = 1.f / (1.f + __expf(-(acc[i][j] + bb[j])));
                    float v = fmaxf((1.f - g) * xa[j] + g * za[j], 0.f);
                    va[j] = v; cs[j] += v; cq[j] += v * v;
                }
                *(float4*)(C + (size_t)r * N + c0) = make_float4(va[0], va[1], va[2], va[3]);
            }
        }
        if (tid < 64) { rs[tid] = 0.f; rq[tid] = 0.f; }
        __syncthreads();
#pragma unroll
        for (int j = 0; j < 4; ++j) {
            atomicAdd(&rs[tx * 4 + j], cs[j]);
            atomicAdd(&rq[tx * 4 + j], cq[j]);
        }
        __syncthreads();
        if (tid < 64) {
            atomicAdd(&g_colsum[N0 + tid], rs[tid]);
            atomicAdd(&g_colsq[N0 + tid], rq[tid]);
        }
    } else {
#pragma unroll
        for (int i = 0; i < 4; ++i) {
            int r = M0 + ty * 4 + i;
            if (r < M) {
                float va[4];
#pragma unroll
                for (int j = 0; j < 4; ++j) {
                    float v = acc[i][j] + bb[j];
                    if (EPI == 1) v = tanhf(v);
                    va[j] = v;
                }
                *(float4*)(C + (size_t)r * N + c0) = make_float4(va[0], va[1], va[2], va[3]);
            }
        }
    }
}

// ---------------- BN stats + apply ----------------
__global__ void bn_stats(const float* __restrict__ gamma, const float* __restrict__ beta) {
    int c = threadIdx.x;  // 512
    float mean = g_colsum[c] * (1.f / (float)NN);
    float var = g_colsq[c] * (1.f / (float)NN) - mean * mean;
    float s = rsqrtf(var + 1e-5f) * gamma[c];
    g_sc[c] = s;
    g_sh[c] = beta[c] - mean * s;
}

__global__ __launch_bounds__(256) void bn_apply(float* __restrict__ out) {
    int i = blockIdx.x * 256 + threadIdx.x;  // exactly NN*HH
    int c = i & (HH - 1);
    out[i] = g_obuf[i] * g_sc[c] + g_sh[c];
}

// ---------------- launch ----------------
extern "C" void kernel_launch(void* const* d_in, const int* in_sizes, int n_in,
                              void* d_out, int out_size, void* d_ws, size_t ws_size,
                              hipStream_t stream) {
    (void)d_ws; (void)ws_size; (void)n_in; (void)out_size;
    const float* x      = (const float*)d_in[0];
    const int*   ei     = (const int*)d_in[1];
    const float* w1     = (const float*)d_in[2];
    const float* b1     = (const float*)d_in[3];
    const float* w2     = (const float*)d_in[4];
    const float* b2     = (const float*)d_in[5];
    const float* w3     = (const float*)d_in[6];
    const float* b3     = (const float*)d_in[7];
    const float* gcn_w  = (const float*)d_in[8];
    const float* gcn_b  = (const float*)d_in[9];
    const float* lin_w  = (const float*)d_in[10];
    const float* lin_b  = (const float*)d_in[11];
    const float* gate_w = (const float*)d_in[12];
    const float* gate_b = (const float*)d_in[13];
    const float* bn_g   = (const float*)d_in[14];
    const float* bn_b   = (const float*)d_in[15];
    float* out = (float*)d_out;
    const int E = in_sizes[1] / 2;

    float* feat = nullptr; float* aggf = nullptr; float* z = nullptr;
    float* xl = nullptr; float* obuf = nullptr;
    hipGetSymbolAddress((void**)&feat, HIP_SYMBOL(g_feat));
    hipGetSymbolAddress((void**)&aggf, HIP_SYMBOL(g_aggf));
    hipGetSymbolAddress((void**)&z,    HIP_SYMBOL(g_z));
    hipGetSymbolAddress((void**)&xl,   HIP_SYMBOL(g_xl));
    hipGetSymbolAddress((void**)&obuf, HIP_SYMBOL(g_obuf));

    zero_init<<<8, 256, 0, stream>>>();
    conv_chain<<<NN, 256, 0, stream>>>(x, w1, b1, w2, b2, w3, b3);
    edge_count<<<(E + 255) / 256, 256, 0, stream>>>(ei, E);
    scan_dinv<<<1, 256, 0, stream>>>();
    bucket_fill<<<(E + 255) / 256, 256, 0, stream>>>(ei, E);
    agg_feat<<<NN, 256, 0, stream>>>();

    dim3 gg(HH / 64, (NN + 63) / 64);
    gemm64<1><<<gg, 256, 0, stream>>>(aggf, gcn_w, gcn_b, z, nullptr, nullptr, NN, HH, LL3);
    gemm64<0><<<gg, 256, 0, stream>>>(feat, lin_w, lin_b, xl, nullptr, nullptr, NN, HH, LL3);
    gemm64<2><<<gg, 256, 0, stream>>>(z, gate_w, gate_b, obuf, xl, z, NN, HH, HH);

    bn_stats<<<1, HH, 0, stream>>>(bn_g, bn_b);
    bn_apply<<<(NN * HH) / 256, 256, 0, stream>>>(out);
}

// Round 6
// 384.637 us; speedup vs baseline: 1.2337x; 1.0038x over previous
//
#include <hip/hip_runtime.h>
#include <hip/hip_bf16.h>
#include <cstddef>

#define NN 2000
#define CC 4
#define LL1 5000
#define LL2 1248   /* (5000-11)/4+1 */
#define LL3 207    /* (1248-11)/6+1 */
#define FSTR 208   /* feat row stride (207 + 1 zero pad) */
#define HH 512
#define EE 64000

// ---------------- device-global scratch ----------------
__device__ float g_feat[NN * FSTR];
__device__ float g_aggf[NN * FSTR];
__device__ float g_z[NN * HH];
__device__ float g_xl[NN * HH];
__device__ float g_obuf[NN * HH];
__device__ float g_dinv[NN];
__device__ float g_colsum[HH];
__device__ float g_colsq[HH];
__device__ int   g_cnt[NN];
__device__ int   g_cursor[NN];
__device__ int   g_off[NN];
__device__ int   g_bucket[EE];

// ---------------- zero / init (every call; graph replay reuses globals) --------
__global__ void zero_init() {
    int i = blockIdx.x * 256 + threadIdx.x;
    if (i < NN) { g_cnt[i] = 0; g_cursor[i] = 0; }
    if (i < HH) { g_colsum[i] = 0.f; g_colsq[i] = 0.f; }
}

// ---------------- per-node conv chain (unchanged structure; feat stride 208) ----------
#define MCH 1256
__global__ __launch_bounds__(256) void conv_chain(
    const float* __restrict__ x,
    const float* __restrict__ w1, const float* __restrict__ b1,
    const float* __restrict__ w2, const float* __restrict__ b2,
    const float* __restrict__ w3, const float* __restrict__ b3)
{
    __shared__ __align__(16) float sm[4 * MCH];
    __shared__ __align__(16) float sy[4 * LL2];

    const int tid = threadIdx.x;
    const int node = blockIdx.x;
    const float* xb = x + (size_t)node * (CC * LL1);

    float w1r[64], b1r[16];
#pragma unroll
    for (int i = 0; i < 64; ++i) w1r[i] = w1[i];
#pragma unroll
    for (int i = 0; i < 16; ++i) b1r[i] = b1[i];

#pragma unroll 1
    for (int c = 0; c < 4; ++c) {
        const int l0 = 1248 * c;
        for (int g4 = tid; g4 < 314; g4 += 256) {
            const int l = l0 + 4 * g4;
            float xs[4][4];
#pragma unroll
            for (int ch = 0; ch < 4; ++ch)
                *(float4*)xs[ch] = *(const float4*)(xb + ch * LL1 + l);
#pragma unroll
            for (int g = 0; g < 4; ++g) {
                float mv[4];
#pragma unroll
                for (int li = 0; li < 4; ++li) {
                    float best = -1e30f;
#pragma unroll
                    for (int j = 0; j < 4; ++j) {
                        int o = g * 4 + j;
                        float v = b1r[o] + w1r[o*4+0]*xs[0][li] + w1r[o*4+1]*xs[1][li]
                                         + w1r[o*4+2]*xs[2][li] + w1r[o*4+3]*xs[3][li];
                        best = fmaxf(best, v);
                    }
                    mv[li] = fmaxf(best, 0.f);
                }
                *(float4*)&sm[g * MCH + 4 * g4] = make_float4(mv[0], mv[1], mv[2], mv[3]);
            }
        }
        __syncthreads();

        const int T0 = 312 * c;
#pragma unroll 1
        for (int pair = 0; pair < 2; ++pair) {
            const float* wp = w2 + 88 * pair;
            float wo[88];
#pragma unroll
            for (int i = 0; i < 88; ++i) wo[i] = wp[i];
            const float bo0 = b2[2 * pair], bo1 = b2[2 * pair + 1];
            for (int T = tid; T < 312; T += 256) {
                float a0 = bo0, a1 = bo1;
#pragma unroll
                for (int i = 0; i < 4; ++i) {
                    const float* mp = sm + i * MCH + 4 * T;
                    float4 u0 = *(const float4*)mp;
                    float4 u1 = *(const float4*)(mp + 4);
                    float4 u2 = *(const float4*)(mp + 8);
                    float v[12] = {u0.x, u0.y, u0.z, u0.w,
                                   u1.x, u1.y, u1.z, u1.w,
                                   u2.x, u2.y, u2.z, u2.w};
#pragma unroll
                    for (int k = 0; k < 11; ++k) {
                        a0 += wo[i * 11 + k] * v[k];
                        a1 += wo[44 + i * 11 + k] * v[k];
                    }
                }
                sy[(2 * pair) * LL2 + T0 + T]     = fmaxf(a0, 0.f);
                sy[(2 * pair + 1) * LL2 + T0 + T] = fmaxf(a1, 0.f);
            }
        }
        __syncthreads();
    }

    if (tid < FSTR) {
        float acc = 0.f;
        if (tid < LL3) {
            acc = b3[0];
#pragma unroll
            for (int i = 0; i < 4; ++i)
#pragma unroll
                for (int k = 0; k < 11; ++k)
                    acc += w3[i * 11 + k] * sy[i * LL2 + 6 * tid + k];
            acc = fmaxf(acc, 0.f);
        }
        g_feat[(size_t)node * FSTR + tid] = acc;
    }
}

// ---------------- edge processing ----------------
__global__ void edge_count(const int* __restrict__ ei, int E) {
    int e = blockIdx.x * 256 + threadIdx.x;
    if (e < E) atomicAdd(&g_cnt[ei[E + e]], 1);
}

__global__ __launch_bounds__(256) void scan_dinv() {
    __shared__ int a[2048], b[2048];
    int tid = threadIdx.x;
    for (int i = tid; i < 2048; i += 256) a[i] = (i < NN) ? g_cnt[i] : 0;
    __syncthreads();
    int* src = a; int* dst = b;
    for (int d = 1; d < 2048; d <<= 1) {
        for (int i = tid; i < 2048; i += 256)
            dst[i] = src[i] + ((i >= d) ? src[i - d] : 0);
        __syncthreads();
        int* t = src; src = dst; dst = t;
    }
    for (int i = tid; i < NN; i += 256) {
        g_off[i] = src[i] - g_cnt[i];
        g_dinv[i] = rsqrtf(1.0f + (float)g_cnt[i]);
    }
}

__global__ void bucket_fill(const int* __restrict__ ei, int E) {
    int e = blockIdx.x * 256 + threadIdx.x;
    if (e < E) {
        int d = ei[E + e];
        int p = atomicAdd(&g_cursor[d], 1);
        g_bucket[g_off[d] + p] = ei[e];
    }
}

// ---------------- aggregate feat over graph (float4 gathers, 4 nodes/block) -------
__global__ __launch_bounds__(256) void agg_feat() {
    const int sub = threadIdx.x >> 6;
    const int lane = threadIdx.x & 63;
    const int d = blockIdx.x * 4 + sub;          // grid 500 -> d < 2000
    if (lane >= 52) return;
    const float di = g_dinv[d];
    const int nb = g_cnt[d];
    const int base = g_off[d];
    const size_t co = (size_t)lane * 4;
    float4 a = *(const float4*)(g_feat + (size_t)d * FSTR + co);
    float ax = a.x * di, ay = a.y * di, az = a.z * di, aw = a.w * di;
    int j = 0;
    for (; j + 1 < nb; j += 2) {
        int s0 = g_bucket[base + j];
        int s1 = g_bucket[base + j + 1];
        float w0 = g_dinv[s0], w1 = g_dinv[s1];
        float4 f0 = *(const float4*)(g_feat + (size_t)s0 * FSTR + co);
        float4 f1 = *(const float4*)(g_feat + (size_t)s1 * FSTR + co);
        ax += f0.x * w0 + f1.x * w1;
        ay += f0.y * w0 + f1.y * w1;
        az += f0.z * w0 + f1.z * w1;
        aw += f0.w * w0 + f1.w * w1;
    }
    if (j < nb) {
        int s = g_bucket[base + j];
        float w = g_dinv[s];
        float4 f = *(const float4*)(g_feat + (size_t)s * FSTR + co);
        ax += f.x * w; ay += f.y * w; az += f.z * w; aw += f.w * w;
    }
    *(float4*)(g_aggf + (size_t)d * FSTR + co) = make_float4(ax * di, ay * di, az * di, aw * di);
}

// ---------------- GEMM 32x32 tile, 256 thr, dbuf, coalesced A ----------------
// z = tanh(aggf @ gcn_w + gcn_b)  [blockIdx.z==0]
// xl =      feat @ lin_w + lin_b  [blockIdx.z==1]
__global__ __launch_bounds__(256) void gemm_zxl(
    const float* __restrict__ gcn_w, const float* __restrict__ gcn_b,
    const float* __restrict__ lin_w, const float* __restrict__ lin_b)
{
    __shared__ float As[2][16][33];
    __shared__ float Bs[2][16][32];
    const int tid = threadIdx.x;
    const int which = blockIdx.z;
    const float* __restrict__ A = which ? g_feat : g_aggf;
    const float* __restrict__ B = which ? lin_w : gcn_w;
    const float* __restrict__ bias = which ? lin_b : gcn_b;
    float* __restrict__ C = which ? g_xl : g_z;
    const int N0 = blockIdx.x * 32, M0 = blockIdx.y * 32;
    const int lr = tid >> 4, lk = tid & 15;       // A loader
    const int bk = tid >> 4, bn = (tid & 15) * 2; // B loader
    const int ty = tid >> 3, tx = tid & 7;        // compute: 1 row x 4 cols

    float acc[4] = {0.f, 0.f, 0.f, 0.f};
    float ra0, ra1; float2 rbv;
    const int r0 = M0 + lr, r1 = M0 + lr + 16;

    ra0 = (r0 < NN) ? A[(size_t)r0 * FSTR + lk] : 0.f;
    ra1 = (r1 < NN) ? A[(size_t)r1 * FSTR + lk] : 0.f;
    rbv = (bk < LL3) ? *(const float2*)(B + (size_t)bk * HH + N0 + bn) : make_float2(0.f, 0.f);
    As[0][lk][lr] = ra0; As[0][lk][lr + 16] = ra1;
    Bs[0][bk][bn] = rbv.x; Bs[0][bk][bn + 1] = rbv.y;
    __syncthreads();

#pragma unroll 1
    for (int kt = 0; kt < 13; ++kt) {             // 13*16 = 208 = FSTR (A pad col = 0)
        const int cur = kt & 1;
        if (kt + 1 < 13) {
            int k0 = (kt + 1) * 16;
            ra0 = (r0 < NN) ? A[(size_t)r0 * FSTR + k0 + lk] : 0.f;
            ra1 = (r1 < NN) ? A[(size_t)r1 * FSTR + k0 + lk] : 0.f;
            int kb = k0 + bk;
            rbv = (kb < LL3) ? *(const float2*)(B + (size_t)kb * HH + N0 + bn) : make_float2(0.f, 0.f);
        }
#pragma unroll
        for (int k = 0; k < 16; ++k) {
            float av = As[cur][k][ty];
            float4 b4 = *(const float4*)&Bs[cur][k][tx * 4];
            acc[0] += av * b4.x; acc[1] += av * b4.y; acc[2] += av * b4.z; acc[3] += av * b4.w;
        }
        if (kt + 1 < 13) {
            const int nxt = cur ^ 1;
            As[nxt][lk][lr] = ra0; As[nxt][lk][lr + 16] = ra1;
            Bs[nxt][bk][bn] = rbv.x; Bs[nxt][bk][bn + 1] = rbv.y;
        }
        __syncthreads();
    }

    const int r = M0 + ty;
    if (r < NN) {
        const int c0 = N0 + tx * 4;
        float4 bb = *(const float4*)(bias + c0);
        float4 v = make_float4(acc[0] + bb.x, acc[1] + bb.y, acc[2] + bb.z, acc[3] + bb.w);
        if (which == 0) { v.x = tanhf(v.x); v.y = tanhf(v.y); v.z = tanhf(v.z); v.w = tanhf(v.w); }
        *(float4*)(C + (size_t)r * HH + c0) = v;
    }
}

// gate GEMM: gpre = z @ gate_w + gate_b, fused sigmoid-gate/residual/relu/colsums
__global__ __launch_bounds__(256) void gemm_gate(
    const float* __restrict__ gate_w, const float* __restrict__ gate_b)
{
    __shared__ float As[2][16][33];
    __shared__ float Bs[2][16][32];
    __shared__ float rs[32], rq[32];
    const int tid = threadIdx.x;
    const float* __restrict__ A = g_z;
    const int N0 = blockIdx.x * 32, M0 = blockIdx.y * 32;
    const int lr = tid >> 4, lk = tid & 15;
    const int bk = tid >> 4, bn = (tid & 15) * 2;
    const int ty = tid >> 3, tx = tid & 7;

    float acc[4] = {0.f, 0.f, 0.f, 0.f};
    float ra0, ra1; float2 rbv;
    const int r0 = M0 + lr, r1 = M0 + lr + 16;

    ra0 = (r0 < NN) ? A[(size_t)r0 * HH + lk] : 0.f;
    ra1 = (r1 < NN) ? A[(size_t)r1 * HH + lk] : 0.f;
    rbv = *(const float2*)(gate_w + (size_t)bk * HH + N0 + bn);
    As[0][lk][lr] = ra0; As[0][lk][lr + 16] = ra1;
    Bs[0][bk][bn] = rbv.x; Bs[0][bk][bn + 1] = rbv.y;
    __syncthreads();

#pragma unroll 1
    for (int kt = 0; kt < 32; ++kt) {
        const int cur = kt & 1;
        if (kt + 1 < 32) {
            int k0 = (kt + 1) * 16;
            ra0 = (r0 < NN) ? A[(size_t)r0 * HH + k0 + lk] : 0.f;
            ra1 = (r1 < NN) ? A[(size_t)r1 * HH + k0 + lk] : 0.f;
            rbv = *(const float2*)(gate_w + (size_t)(k0 + bk) * HH + N0 + bn);
        }
#pragma unroll
        for (int k = 0; k < 16; ++k) {
            float av = As[cur][k][ty];
            float4 b4 = *(const float4*)&Bs[cur][k][tx * 4];
            acc[0] += av * b4.x; acc[1] += av * b4.y; acc[2] += av * b4.z; acc[3] += av * b4.w;
        }
        if (kt + 1 < 32) {
            const int nxt = cur ^ 1;
            As[nxt][lk][lr] = ra0; As[nxt][lk][lr + 16] = ra1;
            Bs[nxt][bk][bn] = rbv.x; Bs[nxt][bk][bn + 1] = rbv.y;
        }
        __syncthreads();
    }

    const int r = M0 + ty;
    const int c0 = N0 + tx * 4;
    float cs[4] = {0.f, 0.f, 0.f, 0.f}, cq[4] = {0.f, 0.f, 0.f, 0.f};
    if (r < NN) {
        float4 bb = *(const float4*)(gate_b + c0);
        float4 xv = *(const float4*)(g_xl + (size_t)r * HH + c0);
        float4 zv = *(const float4*)(g_z + (size_t)r * HH + c0);
        float pre[4] = {acc[0] + bb.x, acc[1] + bb.y, acc[2] + bb.z, acc[3] + bb.w};
        float xa[4] = {xv.x, xv.y, xv.z, xv.w};
        float za[4] = {zv.x, zv.y, zv.z, zv.w};
        float va[4];
#pragma unroll
        for (int j = 0; j < 4; ++j) {
            float g = 1.f / (1.f + __expf(-pre[j]));
            float v = fmaxf((1.f - g) * xa[j] + g * za[j], 0.f);
            va[j] = v; cs[j] = v; cq[j] = v * v;
        }
        *(float4*)(g_obuf + (size_t)r * HH + c0) = make_float4(va[0], va[1], va[2], va[3]);
    }
    if (tid < 32) { rs[tid] = 0.f; rq[tid] = 0.f; }
    __syncthreads();
#pragma unroll
    for (int j = 0; j < 4; ++j) {
        atomicAdd(&rs[tx * 4 + j], cs[j]);
        atomicAdd(&rq[tx * 4 + j], cq[j]);
    }
    __syncthreads();
    if (tid < 32) {
        atomicAdd(&g_colsum[N0 + tid], rs[tid]);
        atomicAdd(&g_colsq[N0 + tid], rq[tid]);
    }
}

// ---------------- BN apply with inline stats ----------------
__global__ __launch_bounds__(256) void bn_apply(const float* __restrict__ gamma,
                                                const float* __restrict__ beta,
                                                float* __restrict__ out) {
    int i = blockIdx.x * 256 + threadIdx.x;  // exactly NN*HH
    int c = i & (HH - 1);
    float mean = g_colsum[c] * (1.f / (float)NN);
    float var = g_colsq[c] * (1.f / (float)NN) - mean * mean;
    float s = rsqrtf(var + 1e-5f) * gamma[c];
    out[i] = g_obuf[i] * s + (beta[c] - mean * s);
}

// ---------------- launch ----------------
extern "C" void kernel_launch(void* const* d_in, const int* in_sizes, int n_in,
                              void* d_out, int out_size, void* d_ws, size_t ws_size,
                              hipStream_t stream) {
    (void)d_ws; (void)ws_size; (void)n_in; (void)out_size;
    const float* x      = (const float*)d_in[0];
    const int*   ei     = (const int*)d_in[1];
    const float* w1     = (const float*)d_in[2];
    const float* b1     = (const float*)d_in[3];
    const float* w2     = (const float*)d_in[4];
    const float* b2     = (const float*)d_in[5];
    const float* w3     = (const float*)d_in[6];
    const float* b3     = (const float*)d_in[7];
    const float* gcn_w  = (const float*)d_in[8];
    const float* gcn_b  = (const float*)d_in[9];
    const float* lin_w  = (const float*)d_in[10];
    const float* lin_b  = (const float*)d_in[11];
    const float* gate_w = (const float*)d_in[12];
    const float* gate_b = (const float*)d_in[13];
    const float* bn_g   = (const float*)d_in[14];
    const float* bn_b   = (const float*)d_in[15];
    float* out = (float*)d_out;
    const int E = in_sizes[1] / 2;

    zero_init<<<8, 256, 0, stream>>>();
    conv_chain<<<NN, 256, 0, stream>>>(x, w1, b1, w2, b2, w3, b3);
    edge_count<<<(E + 255) / 256, 256, 0, stream>>>(ei, E);
    scan_dinv<<<1, 256, 0, stream>>>();
    bucket_fill<<<(E + 255) / 256, 256, 0, stream>>>(ei, E);
    agg_feat<<<NN / 4, 256, 0, stream>>>();

    gemm_zxl<<<dim3(HH / 32, (NN + 31) / 32, 2), 256, 0, stream>>>(gcn_w, gcn_b, lin_w, lin_b);
    gemm_gate<<<dim3(HH / 32, (NN + 31) / 32), 256, 0, stream>>>(gate_w, gate_b);

    bn_apply<<<(NN * HH) / 256, 256, 0, stream>>>(bn_g, bn_b, out);
}